// Round 6
// baseline (400.492 us; speedup 1.0000x reference)
//
#include <hip/hip_runtime.h>
#include <math.h>

#define F_IN 128
#define HID 64
#define NHEAD 4
#define NLAYER 3
#define QSW 832  // unified row: q(256)|k(256)|v(256)|skip(64)

typedef unsigned short ushort_t;
typedef __bf16 bf16x8 __attribute__((ext_vector_type(8)));
typedef unsigned short u16x8 __attribute__((ext_vector_type(8)));
typedef float f32x4 __attribute__((ext_vector_type(4)));

__device__ __forceinline__ ushort_t f2bf(float f) {
  unsigned u = __float_as_uint(f);
  u += 0x7fffu + ((u >> 16) & 1u);  // RNE; inputs finite
  return (ushort_t)(u >> 16);
}
__device__ __forceinline__ float bf2f(ushort_t s) {
  return __uint_as_float(((unsigned)s) << 16);
}
__device__ __forceinline__ float blo(unsigned u) { return __uint_as_float(u << 16); }
__device__ __forceinline__ float bhi(unsigned u) { return __uint_as_float(u & 0xffff0000u); }

// ---------------- CSR build ----------------
__global__ __launch_bounds__(256) void hist_k(const int* __restrict__ dst, int* __restrict__ cnt, int e) {
  int i = blockIdx.x * 256 + threadIdx.x;
  if (i < e) atomicAdd(&cnt[dst[i]], 1);
}
__global__ __launch_bounds__(1024) void scan_block_k(const int* __restrict__ cnt, int* __restrict__ excl,
                                                     int* __restrict__ bsum, int n) {
  __shared__ int tmp[1024];
  int t = threadIdx.x;
  int i = blockIdx.x * 1024 + t;
  int v = (i < n) ? cnt[i] : 0;
  tmp[t] = v;
  __syncthreads();
  for (int off = 1; off < 1024; off <<= 1) {
    int add = (t >= off) ? tmp[t - off] : 0;
    __syncthreads();
    tmp[t] += add;
    __syncthreads();
  }
  if (i < n) excl[i] = tmp[t] - v;
  if (t == 1023) bsum[blockIdx.x] = tmp[1023];
}
// parallel exclusive scan of block sums (nb <= 64)
__global__ __launch_bounds__(64) void scan_bsum_k(int* __restrict__ bsum, int nb) {
  int l = threadIdx.x;
  int orig = (l < nb) ? bsum[l] : 0;
  int v = orig;
  for (int off = 1; off < 64; off <<= 1) {
    int u = __shfl_up(v, off);
    if (l >= off) v += u;
  }
  if (l < nb) bsum[l] = v - orig;
}
__global__ __launch_bounds__(256) void finalize_rowptr_k(const int* __restrict__ excl, const int* __restrict__ bsum,
                                                         int* __restrict__ rowp, int n, int e) {
  int i = blockIdx.x * 256 + threadIdx.x;
  if (i < n) rowp[i] = excl[i] + bsum[i >> 10];
  if (i == 0) rowp[n] = e;
}
__global__ __launch_bounds__(256) void scatter_k(const int* __restrict__ src, const int* __restrict__ dst,
                                                 const int* __restrict__ rowp, int* __restrict__ cur,
                                                 int* __restrict__ srt, int e) {
  int i = blockIdx.x * 256 + threadIdx.x;
  if (i < e) {
    int d = dst[i];
    int pos = rowp[d] + atomicAdd(&cur[d], 1);
    srt[pos] = src[i];
  }
}

// ---------------- weight / bias packing ----------------
// Blocks 0..311: per-layer [Wq|Wk|Wv|Ws] -> 832-wide frag tiles (104/layer).
// Blocks 312..327: lin0 [128,64], 16 tiles. Blocks 328..330: bias rows.
__global__ __launch_bounds__(64) void pack_weights(const float* __restrict__ Wq, const float* __restrict__ Wk,
                                                   const float* __restrict__ Wv, const float* __restrict__ Ws,
                                                   const float* __restrict__ w0,
                                                   const float* __restrict__ bq, const float* __restrict__ bk,
                                                   const float* __restrict__ bv, const float* __restrict__ bs,
                                                   ushort_t* __restrict__ wp_all, ushort_t* __restrict__ wp_lin0,
                                                   float* __restrict__ bp) {
  int b = blockIdx.x, lane = threadIdx.x;
  if (b < 312) {
    int l = b / 104, t = b % 104;
    int ntg = t >> 1, kt = t & 1;
    int col = ntg * 16 + (lane & 15);
    int kb = kt * 32 + (lane >> 4) * 8;
    const float* W;
    int c, stride;
    if (col < 256)      { W = Wq + (long long)l * 64 * 256; c = col;       stride = 256; }
    else if (col < 512) { W = Wk + (long long)l * 64 * 256; c = col - 256; stride = 256; }
    else if (col < 768) { W = Wv + (long long)l * 64 * 256; c = col - 512; stride = 256; }
    else                { W = Ws + (long long)l * 64 * 64;  c = col - 768; stride = 64; }
    ushort_t vals[8];
#pragma unroll
    for (int e = 0; e < 8; e++) vals[e] = f2bf(W[(long long)(kb + e) * stride + c]);
    ushort_t* p = wp_all + (long long)l * (104 * 512) + ((long long)t * 64 + lane) * 8;
    ushort4 lo{vals[0], vals[1], vals[2], vals[3]}, hi{vals[4], vals[5], vals[6], vals[7]};
    *(ushort4*)p = lo;
    *(ushort4*)(p + 4) = hi;
  } else if (b < 328) {
    int t = b - 312;  // 0..15: ntg=t>>2, kt=t&3
    int col = (t >> 2) * 16 + (lane & 15);
    int kb = (t & 3) * 32 + (lane >> 4) * 8;
    ushort_t vals[8];
#pragma unroll
    for (int e = 0; e < 8; e++) vals[e] = f2bf(w0[(long long)(kb + e) * 64 + col]);
    ushort_t* p = wp_lin0 + ((long long)t * 64 + lane) * 8;
    ushort4 lo{vals[0], vals[1], vals[2], vals[3]}, hi{vals[4], vals[5], vals[6], vals[7]};
    *(ushort4*)p = lo;
    *(ushort4*)(p + 4) = hi;
  } else {
    int l = b - 328;  // bias row for layer l
    for (int c = lane; c < QSW; c += 64) {
      float v = (c < 256) ? bq[l * 256 + c]
              : (c < 512) ? bk[l * 256 + c - 256]
              : (c < 768) ? bv[l * 256 + c - 512]
              : bs[l * 64 + c - 768];
      bp[l * QSW + c] = v;
    }
  }
}

// ---------------- MFMA GEMM: C[n,outw](bf16) = A[n,K] @ W + bias ----------------
// Swapped operands: W-frag is the A-operand, activation-frag the B-operand.
// D: node row = lane&15 (+16*mr), out col = n0+nt*16+(lane>>4)*4+r -> ushort4 stores.
template <int K, int AF32>
__global__ __launch_bounds__(256) void gemm_mfma(const void* __restrict__ Av, const ushort_t* __restrict__ Wp,
                                                 const float* __restrict__ bias, ushort_t* __restrict__ C,
                                                 int n, int outw) {
  constexpr int KT = K / 32;
  int lane = threadIdx.x & 63;
  int wv = __builtin_amdgcn_readfirstlane((int)(threadIdx.x >> 6));
  int m0 = (blockIdx.x * 4 + wv) * 64;
  int n0 = blockIdx.y * 64;
  int lr = lane & 15, lq = lane >> 4;

  bf16x8 a[4][KT];
#pragma unroll
  for (int mr = 0; mr < 4; mr++) {
    int row = m0 + mr * 16 + lr;
    if (row >= n) row = n - 1;
    if constexpr (AF32) {
      const float* Af = (const float*)Av;
#pragma unroll
      for (int kt = 0; kt < KT; kt++) {
        const float* p = Af + (long long)row * K + kt * 32 + lq * 8;
        float4 f0 = *(const float4*)p;
        float4 f1 = *(const float4*)(p + 4);
        u16x8 u;
        u[0] = f2bf(f0.x); u[1] = f2bf(f0.y); u[2] = f2bf(f0.z); u[3] = f2bf(f0.w);
        u[4] = f2bf(f1.x); u[5] = f2bf(f1.y); u[6] = f2bf(f1.z); u[7] = f2bf(f1.w);
        a[mr][kt] = __builtin_bit_cast(bf16x8, u);
      }
    } else {
      const ushort_t* Ab = (const ushort_t*)Av;
#pragma unroll
      for (int kt = 0; kt < KT; kt++)
        a[mr][kt] = *(const bf16x8*)(Ab + (long long)row * K + kt * 32 + lq * 8);
    }
  }
  f32x4 acc[4][4];
#pragma unroll
  for (int nt = 0; nt < 4; nt++) {
    float4 b4 = *(const float4*)(bias + n0 + nt * 16 + lq * 4);
    f32x4 bi = {b4.x, b4.y, b4.z, b4.w};
#pragma unroll
    for (int mr = 0; mr < 4; mr++) acc[mr][nt] = bi;
  }
#pragma unroll
  for (int nt = 0; nt < 4; nt++) {
    int ntg = (n0 >> 4) + nt;
    bf16x8 bw[KT];
#pragma unroll
    for (int kt = 0; kt < KT; kt++)
      bw[kt] = *(const bf16x8*)(Wp + ((long long)(ntg * KT + kt) * 64 + lane) * 8);
#pragma unroll
    for (int kt = 0; kt < KT; kt++)
#pragma unroll
      for (int mr = 0; mr < 4; mr++)
        acc[mr][nt] = __builtin_amdgcn_mfma_f32_16x16x32_bf16(bw[kt], a[mr][kt], acc[mr][nt], 0, 0, 0);
  }
#pragma unroll
  for (int mr = 0; mr < 4; mr++) {
    int row = m0 + mr * 16 + lr;
    if (row < n) {
#pragma unroll
      for (int nt = 0; nt < 4; nt++) {
        ushort4 o;
        o.x = f2bf(acc[mr][nt][0]);
        o.y = f2bf(acc[mr][nt][1]);
        o.z = f2bf(acc[mr][nt][2]);
        o.w = f2bf(acc[mr][nt][3]);
        *(ushort4*)(C + (long long)row * outw + n0 + nt * 16 + lq * 4) = o;
      }
    }
  }
}

// ---------------- fused attention + head-mean + skip + relu ----------------
// 4 nodes per wave (serial loop). lane = half*32 + sl; 8 ch/lane covers 256 ch.
// Per iteration: 8 edges (4 per half), defer-max online softmax.
__global__ __launch_bounds__(256) void attn_k(const ushort_t* __restrict__ qs,
                                              const int* __restrict__ rowp, const int* __restrict__ srt,
                                              ushort_t* __restrict__ hn, int n) {
  int wvv = __builtin_amdgcn_readfirstlane((int)(threadIdx.x >> 6));
  int base = (blockIdx.x * 4 + wvv) * 4;
  int lane = threadIdx.x & 63;
  int half = lane >> 5;
  int sl = lane & 31;
#pragma unroll 1
  for (int ni = 0; ni < 4; ni++) {
    int node = base + ni;
    if (node >= n) break;
    const uint4 qu = *(const uint4*)(qs + (long long)node * QSW + sl * 8);
    float qf[8];
    qf[0] = blo(qu.x); qf[1] = bhi(qu.x); qf[2] = blo(qu.y); qf[3] = bhi(qu.y);
    qf[4] = blo(qu.z); qf[5] = bhi(qu.z); qf[6] = blo(qu.w); qf[7] = bhi(qu.w);
    int rs = rowp[node], re = rowp[node + 1];
    int last = re - 1;
    float m = -INFINITY, d = 0.f;
    float a[8];
#pragma unroll
    for (int j = 0; j < 8; j++) a[j] = 0.f;

    for (int i = rs; i < re; i += 8) {
      int b0 = i + half * 4;
      int j0 = min(b0, last), j1 = min(b0 + 1, last), j2 = min(b0 + 2, last), j3 = min(b0 + 3, last);
      int i0 = srt[j0], i1 = srt[j1], i2 = srt[j2], i3 = srt[j3];
      const ushort_t* p0 = qs + (long long)i0 * QSW + 256 + sl * 8;
      const ushort_t* p1 = qs + (long long)i1 * QSW + 256 + sl * 8;
      const ushort_t* p2 = qs + (long long)i2 * QSW + 256 + sl * 8;
      const ushort_t* p3 = qs + (long long)i3 * QSW + 256 + sl * 8;
      uint4 k0 = *(const uint4*)p0;
      uint4 k1 = *(const uint4*)p1;
      uint4 k2 = *(const uint4*)p2;
      uint4 k3 = *(const uint4*)p3;
      uint4 v0 = *(const uint4*)(p0 + 256);
      uint4 v1 = *(const uint4*)(p1 + 256);
      uint4 v2 = *(const uint4*)(p2 + 256);
      uint4 v3 = *(const uint4*)(p3 + 256);
      float t0 = 0.f, t1 = 0.f, t2 = 0.f, t3 = 0.f;
      t0 = fmaf(qf[0], blo(k0.x), t0); t0 = fmaf(qf[1], bhi(k0.x), t0);
      t0 = fmaf(qf[2], blo(k0.y), t0); t0 = fmaf(qf[3], bhi(k0.y), t0);
      t0 = fmaf(qf[4], blo(k0.z), t0); t0 = fmaf(qf[5], bhi(k0.z), t0);
      t0 = fmaf(qf[6], blo(k0.w), t0); t0 = fmaf(qf[7], bhi(k0.w), t0);
      t1 = fmaf(qf[0], blo(k1.x), t1); t1 = fmaf(qf[1], bhi(k1.x), t1);
      t1 = fmaf(qf[2], blo(k1.y), t1); t1 = fmaf(qf[3], bhi(k1.y), t1);
      t1 = fmaf(qf[4], blo(k1.z), t1); t1 = fmaf(qf[5], bhi(k1.z), t1);
      t1 = fmaf(qf[6], blo(k1.w), t1); t1 = fmaf(qf[7], bhi(k1.w), t1);
      t2 = fmaf(qf[0], blo(k2.x), t2); t2 = fmaf(qf[1], bhi(k2.x), t2);
      t2 = fmaf(qf[2], blo(k2.y), t2); t2 = fmaf(qf[3], bhi(k2.y), t2);
      t2 = fmaf(qf[4], blo(k2.z), t2); t2 = fmaf(qf[5], bhi(k2.z), t2);
      t2 = fmaf(qf[6], blo(k2.w), t2); t2 = fmaf(qf[7], bhi(k2.w), t2);
      t3 = fmaf(qf[0], blo(k3.x), t3); t3 = fmaf(qf[1], bhi(k3.x), t3);
      t3 = fmaf(qf[2], blo(k3.y), t3); t3 = fmaf(qf[3], bhi(k3.y), t3);
      t3 = fmaf(qf[4], blo(k3.z), t3); t3 = fmaf(qf[5], bhi(k3.z), t3);
      t3 = fmaf(qf[6], blo(k3.w), t3); t3 = fmaf(qf[7], bhi(k3.w), t3);
      t0 += __shfl_xor(t0, 1); t1 += __shfl_xor(t1, 1); t2 += __shfl_xor(t2, 1); t3 += __shfl_xor(t3, 1);
      t0 += __shfl_xor(t0, 2); t1 += __shfl_xor(t1, 2); t2 += __shfl_xor(t2, 2); t3 += __shfl_xor(t3, 2);
      t0 += __shfl_xor(t0, 4); t1 += __shfl_xor(t1, 4); t2 += __shfl_xor(t2, 4); t3 += __shfl_xor(t3, 4);
      t0 *= 0.125f; t1 *= 0.125f; t2 *= 0.125f; t3 *= 0.125f;  // 1/sqrt(64)
      if (b0 > last) t0 = -INFINITY;
      if (b0 + 1 > last) t1 = -INFINITY;
      if (b0 + 2 > last) t2 = -INFINITY;
      if (b0 + 3 > last) t3 = -INFINITY;
      float lm = fmaxf(fmaxf(t0, t1), fmaxf(t2, t3));
      lm = fmaxf(lm, __shfl_xor(lm, 32));
      if (__any(lm > m + 8.f)) {  // defer-max: rescale only on significant growth
        float mn = fmaxf(m, lm);
        float co = __expf(m - mn);  // first iter: exp(-inf)=0
        d *= co;
#pragma unroll
        for (int j = 0; j < 8; j++) a[j] *= co;
        m = mn;
      }
      float p0e = __expf(t0 - m), p1e = __expf(t1 - m), p2e = __expf(t2 - m), p3e = __expf(t3 - m);
      d += (p0e + p1e) + (p2e + p3e);
      a[0] += p0e * blo(v0.x) + p1e * blo(v1.x) + p2e * blo(v2.x) + p3e * blo(v3.x);
      a[1] += p0e * bhi(v0.x) + p1e * bhi(v1.x) + p2e * bhi(v2.x) + p3e * bhi(v3.x);
      a[2] += p0e * blo(v0.y) + p1e * blo(v1.y) + p2e * blo(v2.y) + p3e * blo(v3.y);
      a[3] += p0e * bhi(v0.y) + p1e * bhi(v1.y) + p2e * bhi(v2.y) + p3e * bhi(v3.y);
      a[4] += p0e * blo(v0.z) + p1e * blo(v1.z) + p2e * blo(v2.z) + p3e * blo(v3.z);
      a[5] += p0e * bhi(v0.z) + p1e * bhi(v1.z) + p2e * bhi(v2.z) + p3e * bhi(v3.z);
      a[6] += p0e * blo(v0.w) + p1e * blo(v1.w) + p2e * blo(v2.w) + p3e * blo(v3.w);
      a[7] += p0e * bhi(v0.w) + p1e * bhi(v1.w) + p2e * bhi(v2.w) + p3e * bhi(v3.w);
    }
    // merge halves (same head at lane^32)
    d += __shfl_xor(d, 32);
#pragma unroll
    for (int j = 0; j < 8; j++) a[j] += __shfl_xor(a[j], 32);
    float inv = (d > 0.f) ? 1.f / d : 0.f;
    float r[8];
#pragma unroll
    for (int j = 0; j < 8; j++) {
      r[j] = a[j] * inv;
      r[j] += __shfl_xor(r[j], 8);   // head ^1
      r[j] += __shfl_xor(r[j], 16);  // head ^2
    }
    if (lane < 8) {
      const u16x8 s8 = *(const u16x8*)(qs + (long long)node * QSW + 768 + lane * 8);
      u16x8 o;
#pragma unroll
      for (int j = 0; j < 8; j++)
        o[j] = f2bf(fmaxf(r[j] * 0.25f + bf2f(s8[j]), 0.f));
      *(u16x8*)(hn + (long long)node * HID + lane * 8) = o;
    }
  }
}

// ---------------- global add pool (run-length; batch is sorted) ----------------
#define POOL_NPB 128
__global__ __launch_bounds__(64) void pool_k(const ushort_t* __restrict__ h, const int* __restrict__ batch,
                                             float* __restrict__ out, int n) {
  int c = threadIdx.x;
  int n0 = blockIdx.x * POOL_NPB;
  int n1 = n0 + POOL_NPB;
  if (n1 > n) n1 = n;
  if (n0 >= n) return;
  float acc = 0.f;
  int g = batch[n0];
  for (int node = n0; node < n1; node++) {
    int gb = batch[node];
    if (gb != g) {
      atomicAdd(&out[g * 64 + c], acc);
      acc = 0.f;
      g = gb;
    }
    acc += bf2f(h[(long long)node * 64 + c]);
  }
  atomicAdd(&out[g * 64 + c], acc);
}

extern "C" void kernel_launch(void* const* d_in, const int* in_sizes, int n_in,
                              void* d_out, int out_size, void* d_ws, size_t ws_size,
                              hipStream_t stream) {
  const float* x  = (const float*)d_in[0];
  const int* ei   = (const int*)d_in[1];
  const int* batch = (const int*)d_in[2];
  const float* w0 = (const float*)d_in[3];
  const float* b0 = (const float*)d_in[4];
  const float* Wq = (const float*)d_in[5];
  const float* bq = (const float*)d_in[6];
  const float* Wk = (const float*)d_in[7];
  const float* bk = (const float*)d_in[8];
  const float* Wv = (const float*)d_in[9];
  const float* bv = (const float*)d_in[10];
  const float* Ws = (const float*)d_in[11];
  const float* bs = (const float*)d_in[12];
  int N = in_sizes[0] / F_IN;
  int E = in_sizes[1] / 2;
  const int* esrc = ei;
  const int* edst = ei + E;

  // ---- workspace layout ----
  float* bp = (float*)d_ws;                               // 3*832 f32
  ushort_t* h0   = (ushort_t*)(bp + 3 * QSW);
  ushort_t* h1   = h0 + (long long)N * HID;
  ushort_t* qsb  = h1 + (long long)N * HID;               // N x 832
  ushort_t* wp_all  = qsb + (long long)N * QSW;           // 3 * 104 * 512
  ushort_t* wp_lin0 = wp_all + 3 * 104 * 512;             // 16 * 512
  int* cnt  = (int*)(wp_lin0 + 16 * 512);
  int* cur  = cnt + N;
  int* excl = cur + N;
  int* rowp = excl + N;
  int* bsum = rowp + N + 1;
  int* srt  = bsum + 64;

  int nbN = (N + 255) / 256;
  int nbE = (E + 255) / 256;
  int sbBlocks = (N + 1023) / 1024;

  // CSR by dst
  hipMemsetAsync(cnt, 0, (size_t)2 * N * sizeof(int), stream);  // cnt + cur contiguous
  hist_k<<<nbE, 256, 0, stream>>>(edst, cnt, E);
  scan_block_k<<<sbBlocks, 1024, 0, stream>>>(cnt, excl, bsum, N);
  scan_bsum_k<<<1, 64, 0, stream>>>(bsum, sbBlocks);
  finalize_rowptr_k<<<nbN, 256, 0, stream>>>(excl, bsum, rowp, N, E);
  scatter_k<<<nbE, 256, 0, stream>>>(esrc, edst, rowp, cur, srt, E);

  // weight/bias packing (single kernel)
  pack_weights<<<331, 64, 0, stream>>>(Wq, Wk, Wv, Ws, w0, bq, bk, bv, bs, wp_all, wp_lin0, bp);

  int mBlocks = (N + 255) / 256;

  // h0 = x @ lin0_w + lin0_b  (A fp32 direct)
  gemm_mfma<128, 1><<<dim3(mBlocks, 1), 256, 0, stream>>>(x, wp_lin0, b0, h0, N, HID);

  ushort_t* hc = h0;
  ushort_t* hx = h1;
  for (int l = 0; l < NLAYER; l++) {
    gemm_mfma<64, 0><<<dim3(mBlocks, 13), 256, 0, stream>>>(hc, wp_all + (long long)l * 104 * 512,
                                                            bp + l * QSW, qsb, N, QSW);
    attn_k<<<(N + 15) / 16, 256, 0, stream>>>(qsb, rowp, srt, hx, N);
    ushort_t* t = hc; hc = hx; hx = t;
  }

  hipMemsetAsync(d_out, 0, (size_t)out_size * sizeof(float), stream);
  pool_k<<<(N + POOL_NPB - 1) / POOL_NPB, 64, 0, stream>>>(hc, batch, (float*)d_out, N);
}

// Round 7
// 332.952 us; speedup vs baseline: 1.2029x; 1.2029x over previous
//
#include <hip/hip_runtime.h>
#include <math.h>

#define F_IN 128
#define HID 64
#define NLAYER 3
#define QSW 832     // fused gemm output cols: q(256)|k(256)|v(256)|skip(64)
#define QS_ROW 320  // qs row: q(256)|skip(64) bf16
#define KV_ROW 512  // kv row: K(256)|V(256) fp8 bytes

typedef unsigned short ushort_t;
typedef __bf16 bf16x8 __attribute__((ext_vector_type(8)));
typedef unsigned short u16x8 __attribute__((ext_vector_type(8)));
typedef float f32x4 __attribute__((ext_vector_type(4)));
typedef float f32x2 __attribute__((ext_vector_type(2)));

__device__ __forceinline__ ushort_t f2bf(float f) {
  unsigned u = __float_as_uint(f);
  u += 0x7fffu + ((u >> 16) & 1u);  // RNE; inputs finite
  return (ushort_t)(u >> 16);
}
__device__ __forceinline__ float bf2f(ushort_t s) {
  return __uint_as_float(((unsigned)s) << 16);
}
__device__ __forceinline__ float blo(unsigned u) { return __uint_as_float(u << 16); }
__device__ __forceinline__ float bhi(unsigned u) { return __uint_as_float(u & 0xffff0000u); }

// decode 8 fp8(e4m3) bytes -> 8 floats
__device__ __forceinline__ void dec8(uint2 u, float* f) {
  f32x2 a0 = __builtin_amdgcn_cvt_pk_f32_fp8((int)u.x, false);
  f32x2 a1 = __builtin_amdgcn_cvt_pk_f32_fp8((int)u.x, true);
  f32x2 a2 = __builtin_amdgcn_cvt_pk_f32_fp8((int)u.y, false);
  f32x2 a3 = __builtin_amdgcn_cvt_pk_f32_fp8((int)u.y, true);
  f[0] = a0[0]; f[1] = a0[1]; f[2] = a1[0]; f[3] = a1[1];
  f[4] = a2[0]; f[5] = a2[1]; f[6] = a3[0]; f[7] = a3[1];
}

// ---------------- CSR build ----------------
__global__ __launch_bounds__(256) void hist_k(const int* __restrict__ dst, int* __restrict__ cnt, int e) {
  int i = blockIdx.x * 256 + threadIdx.x;
  if (i < e) atomicAdd(&cnt[dst[i]], 1);
}
__global__ __launch_bounds__(1024) void scan_block_k(const int* __restrict__ cnt, int* __restrict__ excl,
                                                     int* __restrict__ bsum, int n) {
  __shared__ int tmp[1024];
  int t = threadIdx.x;
  int i = blockIdx.x * 1024 + t;
  int v = (i < n) ? cnt[i] : 0;
  tmp[t] = v;
  __syncthreads();
  for (int off = 1; off < 1024; off <<= 1) {
    int add = (t >= off) ? tmp[t - off] : 0;
    __syncthreads();
    tmp[t] += add;
    __syncthreads();
  }
  if (i < n) excl[i] = tmp[t] - v;
  if (t == 1023) bsum[blockIdx.x] = tmp[1023];
}
// parallel exclusive scan of block sums (nb <= 64)
__global__ __launch_bounds__(64) void scan_bsum_k(int* __restrict__ bsum, int nb) {
  int l = threadIdx.x;
  int orig = (l < nb) ? bsum[l] : 0;
  int v = orig;
  for (int off = 1; off < 64; off <<= 1) {
    int u = __shfl_up(v, off);
    if (l >= off) v += u;
  }
  if (l < nb) bsum[l] = v - orig;
}
// fused: rowp finalize + edge scatter (rowp recomputed inline from excl+bsum)
__global__ __launch_bounds__(256) void scatter_rowptr_k(const int* __restrict__ src, const int* __restrict__ dst,
                                                        const int* __restrict__ excl, const int* __restrict__ bsum,
                                                        int* __restrict__ cur, int* __restrict__ rowp,
                                                        int* __restrict__ srt, int n, int e) {
  int i = blockIdx.x * 256 + threadIdx.x;
  if (i < n) rowp[i] = excl[i] + bsum[i >> 10];
  if (i == 0) rowp[n] = e;
  if (i < e) {
    int d = dst[i];
    int pos = excl[d] + bsum[d >> 10] + atomicAdd(&cur[d], 1);
    srt[pos] = src[i];
  }
}

// ---------------- weight / bias packing ----------------
// Blocks 0..311: per-layer [Wq|Wk|Wv|Ws] -> 832-wide frag tiles (104/layer).
// Blocks 312..327: lin0 [128,64], 16 tiles. Blocks 328..330: bias rows.
__global__ __launch_bounds__(64) void pack_weights(const float* __restrict__ Wq, const float* __restrict__ Wk,
                                                   const float* __restrict__ Wv, const float* __restrict__ Ws,
                                                   const float* __restrict__ w0,
                                                   const float* __restrict__ bq, const float* __restrict__ bk,
                                                   const float* __restrict__ bv, const float* __restrict__ bs,
                                                   ushort_t* __restrict__ wp_all, ushort_t* __restrict__ wp_lin0,
                                                   float* __restrict__ bp) {
  int b = blockIdx.x, lane = threadIdx.x;
  if (b < 312) {
    int l = b / 104, t = b % 104;
    int ntg = t >> 1, kt = t & 1;
    int col = ntg * 16 + (lane & 15);
    int kb = kt * 32 + (lane >> 4) * 8;
    const float* W;
    int c, stride;
    if (col < 256)      { W = Wq + (long long)l * 64 * 256; c = col;       stride = 256; }
    else if (col < 512) { W = Wk + (long long)l * 64 * 256; c = col - 256; stride = 256; }
    else if (col < 768) { W = Wv + (long long)l * 64 * 256; c = col - 512; stride = 256; }
    else                { W = Ws + (long long)l * 64 * 64;  c = col - 768; stride = 64; }
    ushort_t vals[8];
#pragma unroll
    for (int e = 0; e < 8; e++) vals[e] = f2bf(W[(long long)(kb + e) * stride + c]);
    ushort_t* p = wp_all + (long long)l * (104 * 512) + ((long long)t * 64 + lane) * 8;
    ushort4 lo{vals[0], vals[1], vals[2], vals[3]}, hi{vals[4], vals[5], vals[6], vals[7]};
    *(ushort4*)p = lo;
    *(ushort4*)(p + 4) = hi;
  } else if (b < 328) {
    int t = b - 312;  // 0..15: ntg=t>>2, kt=t&3
    int col = (t >> 2) * 16 + (lane & 15);
    int kb = (t & 3) * 32 + (lane >> 4) * 8;
    ushort_t vals[8];
#pragma unroll
    for (int e = 0; e < 8; e++) vals[e] = f2bf(w0[(long long)(kb + e) * 64 + col]);
    ushort_t* p = wp_lin0 + ((long long)t * 64 + lane) * 8;
    ushort4 lo{vals[0], vals[1], vals[2], vals[3]}, hi{vals[4], vals[5], vals[6], vals[7]};
    *(ushort4*)p = lo;
    *(ushort4*)(p + 4) = hi;
  } else {
    int l = b - 328;  // bias row for layer l
    for (int c = lane; c < QSW; c += 64) {
      float v = (c < 256) ? bq[l * 256 + c]
              : (c < 512) ? bk[l * 256 + c - 256]
              : (c < 768) ? bv[l * 256 + c - 512]
              : bs[l * 64 + c - 768];
      bp[l * QSW + c] = v;
    }
  }
}

// ---------------- MFMA GEMM ----------------
// Swapped operands: W-frag = A-operand, activation-frag = B-operand.
// D: node row = lane&15 (+16*mr), out col = n0+nt*16+(lane>>4)*4+r.
// MODE 0: bf16 out [n,HID] (lin0). MODE 1: fused q/skip->bf16 qs, K/V->fp8 kv.
template <int K, int AF32, int MODE>
__global__ __launch_bounds__(256) void gemm_mfma(const void* __restrict__ Av, const ushort_t* __restrict__ Wp,
                                                 const float* __restrict__ bias, ushort_t* __restrict__ Cq,
                                                 unsigned char* __restrict__ Ckv, int n) {
  constexpr int KT = K / 32;
  int lane = threadIdx.x & 63;
  int wv = __builtin_amdgcn_readfirstlane((int)(threadIdx.x >> 6));
  int m0 = (blockIdx.x * 4 + wv) * 64;
  int n0 = blockIdx.y * 64;
  int lr = lane & 15, lq = lane >> 4;

  bf16x8 a[4][KT];
#pragma unroll
  for (int mr = 0; mr < 4; mr++) {
    int row = m0 + mr * 16 + lr;
    if (row >= n) row = n - 1;
    if constexpr (AF32) {
      const float* Af = (const float*)Av;
#pragma unroll
      for (int kt = 0; kt < KT; kt++) {
        const float* p = Af + (long long)row * K + kt * 32 + lq * 8;
        float4 f0 = *(const float4*)p;
        float4 f1 = *(const float4*)(p + 4);
        u16x8 u;
        u[0] = f2bf(f0.x); u[1] = f2bf(f0.y); u[2] = f2bf(f0.z); u[3] = f2bf(f0.w);
        u[4] = f2bf(f1.x); u[5] = f2bf(f1.y); u[6] = f2bf(f1.z); u[7] = f2bf(f1.w);
        a[mr][kt] = __builtin_bit_cast(bf16x8, u);
      }
    } else {
      const ushort_t* Ab = (const ushort_t*)Av;
#pragma unroll
      for (int kt = 0; kt < KT; kt++)
        a[mr][kt] = *(const bf16x8*)(Ab + (long long)row * K + kt * 32 + lq * 8);
    }
  }
  f32x4 acc[4][4];
#pragma unroll
  for (int nt = 0; nt < 4; nt++) {
    float4 b4 = *(const float4*)(bias + n0 + nt * 16 + lq * 4);
    f32x4 bi = {b4.x, b4.y, b4.z, b4.w};
#pragma unroll
    for (int mr = 0; mr < 4; mr++) acc[mr][nt] = bi;
  }
#pragma unroll
  for (int nt = 0; nt < 4; nt++) {
    int ntg = (n0 >> 4) + nt;
    bf16x8 bw[KT];
#pragma unroll
    for (int kt = 0; kt < KT; kt++)
      bw[kt] = *(const bf16x8*)(Wp + ((long long)(ntg * KT + kt) * 64 + lane) * 8);
#pragma unroll
    for (int kt = 0; kt < KT; kt++)
#pragma unroll
      for (int mr = 0; mr < 4; mr++)
        acc[mr][nt] = __builtin_amdgcn_mfma_f32_16x16x32_bf16(bw[kt], a[mr][kt], acc[mr][nt], 0, 0, 0);
  }
#pragma unroll
  for (int mr = 0; mr < 4; mr++) {
    int row = m0 + mr * 16 + lr;
    if (row >= n) continue;
    if constexpr (MODE == 0) {
#pragma unroll
      for (int nt = 0; nt < 4; nt++) {
        ushort4 o{f2bf(acc[mr][nt][0]), f2bf(acc[mr][nt][1]), f2bf(acc[mr][nt][2]), f2bf(acc[mr][nt][3])};
        *(ushort4*)(Cq + (long long)row * HID + n0 + nt * 16 + lq * 4) = o;
      }
    } else {
      if (blockIdx.y < 4) {  // q -> bf16
#pragma unroll
        for (int nt = 0; nt < 4; nt++) {
          ushort4 o{f2bf(acc[mr][nt][0]), f2bf(acc[mr][nt][1]), f2bf(acc[mr][nt][2]), f2bf(acc[mr][nt][3])};
          *(ushort4*)(Cq + (long long)row * QS_ROW + n0 + nt * 16 + lq * 4) = o;
        }
      } else if (blockIdx.y < 12) {  // K/V -> fp8 e4m3
#pragma unroll
        for (int nt = 0; nt < 4; nt++) {
          int c = n0 - 256 + nt * 16 + lq * 4;
          int pk = __builtin_amdgcn_cvt_pk_fp8_f32(acc[mr][nt][0], acc[mr][nt][1], 0, false);
          pk = __builtin_amdgcn_cvt_pk_fp8_f32(acc[mr][nt][2], acc[mr][nt][3], pk, true);
          *(unsigned*)(Ckv + (long long)row * KV_ROW + c) = (unsigned)pk;
        }
      } else {  // skip -> bf16
#pragma unroll
        for (int nt = 0; nt < 4; nt++) {
          int c = n0 - 768 + nt * 16 + lq * 4;
          ushort4 o{f2bf(acc[mr][nt][0]), f2bf(acc[mr][nt][1]), f2bf(acc[mr][nt][2]), f2bf(acc[mr][nt][3])};
          *(ushort4*)(Cq + (long long)row * QS_ROW + 256 + c) = o;
        }
      }
    }
  }
}

// ---------------- fused attention + head-mean + skip + relu ----------------
// 1 node/wave. lane = half*32 + sl; sl covers 256 ch as 8 fp8/lane.
// Per iteration: 8 edges (4 per half), fp8 K/V (8B loads), defer-max softmax.
__global__ __launch_bounds__(256) void attn_k(const ushort_t* __restrict__ qs,
                                              const unsigned char* __restrict__ kv,
                                              const int* __restrict__ rowp, const int* __restrict__ srt,
                                              ushort_t* __restrict__ hn, int n) {
  int wvv = __builtin_amdgcn_readfirstlane((int)(threadIdx.x >> 6));
  int node = blockIdx.x * 4 + wvv;
  if (node >= n) return;
  int lane = threadIdx.x & 63;
  int half = lane >> 5;
  int sl = lane & 31;
  const uint4 qu = *(const uint4*)(qs + (long long)node * QS_ROW + sl * 8);
  float qf[8];
  qf[0] = blo(qu.x); qf[1] = bhi(qu.x); qf[2] = blo(qu.y); qf[3] = bhi(qu.y);
  qf[4] = blo(qu.z); qf[5] = bhi(qu.z); qf[6] = blo(qu.w); qf[7] = bhi(qu.w);
  int rs = rowp[node], re = rowp[node + 1];
  int last = re - 1;
  float m = -INFINITY, d = 0.f;
  float a[8];
#pragma unroll
  for (int j = 0; j < 8; j++) a[j] = 0.f;

  for (int i = rs; i < re; i += 8) {
    int b0 = i + half * 4;
    int j0 = min(b0, last), j1 = min(b0 + 1, last), j2 = min(b0 + 2, last), j3 = min(b0 + 3, last);
    int i0 = srt[j0], i1 = srt[j1], i2 = srt[j2], i3 = srt[j3];
    const unsigned char* p0 = kv + (long long)i0 * KV_ROW + sl * 8;
    const unsigned char* p1 = kv + (long long)i1 * KV_ROW + sl * 8;
    const unsigned char* p2 = kv + (long long)i2 * KV_ROW + sl * 8;
    const unsigned char* p3 = kv + (long long)i3 * KV_ROW + sl * 8;
    uint2 k0 = *(const uint2*)p0;
    uint2 k1 = *(const uint2*)p1;
    uint2 k2 = *(const uint2*)p2;
    uint2 k3 = *(const uint2*)p3;
    uint2 v0 = *(const uint2*)(p0 + 256);
    uint2 v1 = *(const uint2*)(p1 + 256);
    uint2 v2 = *(const uint2*)(p2 + 256);
    uint2 v3 = *(const uint2*)(p3 + 256);
    float kf0[8], kf1[8], kf2[8], kf3[8];
    dec8(k0, kf0); dec8(k1, kf1); dec8(k2, kf2); dec8(k3, kf3);
    float t0 = 0.f, t1 = 0.f, t2 = 0.f, t3 = 0.f;
#pragma unroll
    for (int j = 0; j < 8; j++) {
      t0 = fmaf(qf[j], kf0[j], t0);
      t1 = fmaf(qf[j], kf1[j], t1);
      t2 = fmaf(qf[j], kf2[j], t2);
      t3 = fmaf(qf[j], kf3[j], t3);
    }
    t0 += __shfl_xor(t0, 1); t1 += __shfl_xor(t1, 1); t2 += __shfl_xor(t2, 1); t3 += __shfl_xor(t3, 1);
    t0 += __shfl_xor(t0, 2); t1 += __shfl_xor(t1, 2); t2 += __shfl_xor(t2, 2); t3 += __shfl_xor(t3, 2);
    t0 += __shfl_xor(t0, 4); t1 += __shfl_xor(t1, 4); t2 += __shfl_xor(t2, 4); t3 += __shfl_xor(t3, 4);
    t0 *= 0.125f; t1 *= 0.125f; t2 *= 0.125f; t3 *= 0.125f;  // 1/sqrt(64)
    if (b0 > last) t0 = -INFINITY;
    if (b0 + 1 > last) t1 = -INFINITY;
    if (b0 + 2 > last) t2 = -INFINITY;
    if (b0 + 3 > last) t3 = -INFINITY;
    float lm = fmaxf(fmaxf(t0, t1), fmaxf(t2, t3));
    lm = fmaxf(lm, __shfl_xor(lm, 32));
    if (__any(lm > m + 8.f)) {  // defer-max: rescale only on significant growth
      float mn = fmaxf(m, lm);
      float co = __expf(m - mn);  // first iter: exp(-inf)=0
      d *= co;
#pragma unroll
      for (int j = 0; j < 8; j++) a[j] *= co;
      m = mn;
    }
    float p0e = __expf(t0 - m), p1e = __expf(t1 - m), p2e = __expf(t2 - m), p3e = __expf(t3 - m);
    d += (p0e + p1e) + (p2e + p3e);
    float vf0[8], vf1[8], vf2[8], vf3[8];
    dec8(v0, vf0); dec8(v1, vf1); dec8(v2, vf2); dec8(v3, vf3);
#pragma unroll
    for (int j = 0; j < 8; j++)
      a[j] += fmaf(p0e, vf0[j], p1e * vf1[j]) + fmaf(p2e, vf2[j], p3e * vf3[j]);
  }
  // merge halves (same head-channel at lane^32)
  d += __shfl_xor(d, 32);
#pragma unroll
  for (int j = 0; j < 8; j++) a[j] += __shfl_xor(a[j], 32);
  float inv = (d > 0.f) ? 1.f / d : 0.f;
  float r[8];
#pragma unroll
  for (int j = 0; j < 8; j++) {
    r[j] = a[j] * inv;
    r[j] += __shfl_xor(r[j], 8);   // head ^1
    r[j] += __shfl_xor(r[j], 16);  // head ^2
  }
  if (lane < 8) {
    const u16x8 s8 = *(const u16x8*)(qs + (long long)node * QS_ROW + 256 + lane * 8);
    u16x8 o;
#pragma unroll
    for (int j = 0; j < 8; j++)
      o[j] = f2bf(fmaxf(r[j] * 0.25f + bf2f(s8[j]), 0.f));
    *(u16x8*)(hn + (long long)node * HID + lane * 8) = o;
  }
}

// ---------------- global add pool (run-length; batch is sorted) ----------------
#define POOL_NPB 128
__global__ __launch_bounds__(64) void pool_k(const ushort_t* __restrict__ h, const int* __restrict__ batch,
                                             float* __restrict__ out, int n) {
  int c = threadIdx.x;
  int n0 = blockIdx.x * POOL_NPB;
  int n1 = n0 + POOL_NPB;
  if (n1 > n) n1 = n;
  if (n0 >= n) return;
  float acc = 0.f;
  int g = batch[n0];
  for (int node = n0; node < n1; node++) {
    int gb = batch[node];
    if (gb != g) {
      atomicAdd(&out[g * 64 + c], acc);
      acc = 0.f;
      g = gb;
    }
    acc += bf2f(h[(long long)node * 64 + c]);
  }
  atomicAdd(&out[g * 64 + c], acc);
}

extern "C" void kernel_launch(void* const* d_in, const int* in_sizes, int n_in,
                              void* d_out, int out_size, void* d_ws, size_t ws_size,
                              hipStream_t stream) {
  const float* x  = (const float*)d_in[0];
  const int* ei   = (const int*)d_in[1];
  const int* batch = (const int*)d_in[2];
  const float* w0 = (const float*)d_in[3];
  const float* b0 = (const float*)d_in[4];
  const float* Wq = (const float*)d_in[5];
  const float* bq = (const float*)d_in[6];
  const float* Wk = (const float*)d_in[7];
  const float* bk = (const float*)d_in[8];
  const float* Wv = (const float*)d_in[9];
  const float* bv = (const float*)d_in[10];
  const float* Ws = (const float*)d_in[11];
  const float* bs = (const float*)d_in[12];
  int N = in_sizes[0] / F_IN;
  int E = in_sizes[1] / 2;
  const int* esrc = ei;
  const int* edst = ei + E;

  // ---- workspace layout ----
  float* bp = (float*)d_ws;                                   // 3*832 f32
  unsigned char* kvb = (unsigned char*)(bp + 3 * QSW);        // N*512 fp8
  ushort_t* h0 = (ushort_t*)(kvb + (size_t)N * KV_ROW);
  ushort_t* h1 = h0 + (long long)N * HID;
  ushort_t* qs = h1 + (long long)N * HID;                     // N x 320 bf16
  ushort_t* wp_all  = qs + (long long)N * QS_ROW;             // 3 * 104 * 512
  ushort_t* wp_lin0 = wp_all + 3 * 104 * 512;                 // 16 * 512
  int* cnt  = (int*)(wp_lin0 + 16 * 512);
  int* cur  = cnt + N;
  int* excl = cur + N;
  int* rowp = excl + N;
  int* bsum = rowp + N + 1;
  int* srt  = bsum + 64;

  int nbE = (E + 255) / 256;
  int sbBlocks = (N + 1023) / 1024;

  // CSR by dst
  hipMemsetAsync(cnt, 0, (size_t)2 * N * sizeof(int), stream);  // cnt + cur contiguous
  hist_k<<<nbE, 256, 0, stream>>>(edst, cnt, E);
  scan_block_k<<<sbBlocks, 1024, 0, stream>>>(cnt, excl, bsum, N);
  scan_bsum_k<<<1, 64, 0, stream>>>(bsum, sbBlocks);
  scatter_rowptr_k<<<nbE, 256, 0, stream>>>(esrc, edst, excl, bsum, cur, rowp, srt, N, E);

  // weight/bias packing (single kernel)
  pack_weights<<<331, 64, 0, stream>>>(Wq, Wk, Wv, Ws, w0, bq, bk, bv, bs, wp_all, wp_lin0, bp);

  int mBlocks = (N + 255) / 256;

  // h0 = x @ lin0_w + lin0_b  (A fp32 direct)
  gemm_mfma<128, 1, 0><<<dim3(mBlocks, 1), 256, 0, stream>>>(x, wp_lin0, b0, h0, nullptr, N);

  ushort_t* hc = h0;
  ushort_t* hx = h1;
  for (int l = 0; l < NLAYER; l++) {
    gemm_mfma<64, 0, 1><<<dim3(mBlocks, 13), 256, 0, stream>>>(hc, wp_all + (long long)l * 104 * 512,
                                                               bp + l * QSW, qs, kvb, N);
    attn_k<<<(N + 3) / 4, 256, 0, stream>>>(qs, kvb, rowp, srt, hx, N);
    ushort_t* t = hc; hc = hx; hx = t;
  }

  hipMemsetAsync(d_out, 0, (size_t)out_size * sizeof(float), stream);
  pool_k<<<(N + POOL_NPB - 1) / POOL_NPB, 64, 0, stream>>>(hc, batch, (float*)d_out, N);
}